// Round 3
// 494.557 us; speedup vs baseline: 1.0237x; 1.0237x over previous
//
#include <hip/hip_runtime.h>

#define EPS 0.001f
#define HW_POS 1024          // 32*32 spatial positions per image
#define NCH 256              // channels
#define NCG 64               // channel groups of 4 (float4)
#define NB 256               // batch
#define NP 4                 // partitions
#define PS 64                // images per partition
#define SPLIT 4              // blocks per image
#define POS_PER_BLOCK (HW_POS / SPLIT)   // 256 positions per block
#define N_PER_PC 65536.0f    // PS * HW_POS elements per (partition, channel)

typedef float f32x4 __attribute__((ext_vector_type(4)));

// ---------------- Kernel 0: zero the 8 KB accumulator region -----------------
// Workspace footprint is EXACTLY the original 8 KB (asum | asq); sc/sh are
// computed IN PLACE over asum/asq by k_finalize, so no extra ws is touched.
__global__ __launch_bounds__(256) void k_zero(float* __restrict__ acc) {
    const int i = threadIdx.x;
    #pragma unroll
    for (int k = 0; k < 8; ++k) acc[k * 256 + i] = 0.f;
}

// ---------------- Kernel 1: per-(partition,channel) sums via atomics ---------
// grid = NB*SPLIT blocks indexed by SHUFFLED position j (so p = j>>6), 256
// threads. Thread t: cg = t&63 (float4 channel group), wave id t>>6 = spatial
// phase. Each wave-load is 64 consecutive float4 = 1 KiB, perfectly coalesced.
// Reads are REGULAR (not nt) on purpose: they populate L3 so k_norm's re-read
// hits the Infinity Cache (x = 256 MiB = exactly L3 size).
__global__ __launch_bounds__(256) void k_partial(const float4* __restrict__ x,
                                                 const int* __restrict__ perm,
                                                 float* __restrict__ asum,
                                                 float* __restrict__ asq) {
    const int slot  = blockIdx.x;        // j*SPLIT + chunk
    const int j     = slot >> 2;
    const int chunk = slot & (SPLIT - 1);
    const int b     = perm[j];
    const int p     = j >> 6;            // partition
    const int t     = threadIdx.x;
    const int cg    = t & 63;
    const int srow  = t >> 6;

    const float4* xb = x + (size_t)b * (HW_POS * NCG);
    const int s0 = chunk * POS_PER_BLOCK;

    float4 s = make_float4(0.f, 0.f, 0.f, 0.f);
    float4 q = make_float4(0.f, 0.f, 0.f, 0.f);
    #pragma unroll 8
    for (int si = s0 + srow; si < s0 + POS_PER_BLOCK; si += 4) {
        float4 v = xb[(size_t)si * NCG + cg];
        s.x += v.x; s.y += v.y; s.z += v.z; s.w += v.w;
        q.x += v.x * v.x; q.y += v.y * v.y; q.z += v.z * v.z; q.w += v.w * v.w;
    }

    __shared__ float4 ls[4][64];
    __shared__ float4 lq[4][64];
    ls[srow][cg] = s;
    lq[srow][cg] = q;
    __syncthreads();

    if (srow == 0) {
        float4 a0 = ls[0][cg], a1 = ls[1][cg], a2 = ls[2][cg], a3 = ls[3][cg];
        float4 b0 = lq[0][cg], b1 = lq[1][cg], b2 = lq[2][cg], b3 = lq[3][cg];
        float ts[4] = { a0.x + a1.x + a2.x + a3.x,
                        a0.y + a1.y + a2.y + a3.y,
                        a0.z + a1.z + a2.z + a3.z,
                        a0.w + a1.w + a2.w + a3.w };
        float tq[4] = { b0.x + b1.x + b2.x + b3.x,
                        b0.y + b1.y + b2.y + b3.y,
                        b0.z + b1.z + b2.z + b3.z,
                        b0.w + b1.w + b2.w + b3.w };
        float* sp = asum + p * NCH + cg * 4;
        float* qp = asq  + p * NCH + cg * 4;
        #pragma unroll
        for (int k = 0; k < 4; ++k) {
            atomicAdd(sp + k, ts[k]);
            atomicAdd(qp + k, tq[k]);
        }
    }
}

// ---------------- Kernel 2: finalize fused affine coefficients IN PLACE ------
// One tiny block: asum[idx] <- sc = gamma*rsqrt(var+eps),
//                 asq [idx] <- sh = beta - mean*sc.
// Each thread reads and writes only its own idx (no cross-thread deps), so
// the in-place transform is race-free. Keeps workspace at 8 KB.
__global__ __launch_bounds__(256) void k_finalize(float* __restrict__ asum,
                                                  float* __restrict__ asq,
                                                  const float* __restrict__ gamma,
                                                  const float* __restrict__ beta) {
    const int i = threadIdx.x;
    #pragma unroll
    for (int k = 0; k < 4; ++k) {
        const int idx = k * 256 + i;          // idx = p*NCH + c, 0..1023
        const float s    = asum[idx];
        const float q    = asq [idx];
        const float mean = s * (1.0f / N_PER_PC);
        const float var  = q * (1.0f / N_PER_PC) - mean * mean;
        const float inv  = rsqrtf(var + EPS);
        const float scv  = gamma[idx] * inv;
        asum[idx] = scv;                      // sc
        asq [idx] = beta[idx] - mean * scv;   // sh
    }
}

// ---------------- Kernel 3: normalize (non-temporal streaming) ---------------
// Blocks walk in REVERSE order vs k_partial so the L3-resident tail of x is
// re-read first. Both the x loads and the out stores are NON-TEMPORAL:
//  - out is never re-read -> nt stores keep it from evicting x out of L3.
//  - each x line is dead after this read -> nt load marks it evict-first.
// This should convert pass-2 x reads from HBM fetches into L3 hits.
__global__ __launch_bounds__(256) void k_norm(const float4* __restrict__ x,
                                              const float4* __restrict__ sc4,
                                              const float4* __restrict__ sh4,
                                              const int* __restrict__ perm,
                                              float4* __restrict__ out) {
    const int blk   = (int)gridDim.x - 1 - (int)blockIdx.x;   // reverse order
    const int j     = blk >> 2;
    const int chunk = blk & (SPLIT - 1);
    const int b     = perm[j];
    const int p     = j >> 6;
    const int t     = threadIdx.x;
    const int cg    = t & 63;
    const int srow  = t >> 6;

    // Fused affine coefficients: two coalesced 16B loads (L2 hits).
    const float4 sc = sc4[p * NCG + cg];
    const float4 sh = sh4[p * NCG + cg];

    const float4* xb = x   + (size_t)b * (HW_POS * NCG);
    float4*       ob = out + (size_t)b * (HW_POS * NCG);
    const int s0 = chunk * POS_PER_BLOCK;

    #pragma unroll 8
    for (int si = s0 + srow; si < s0 + POS_PER_BLOCK; si += 4) {
        const size_t idx = (size_t)si * NCG + cg;
        f32x4 v = __builtin_nontemporal_load((const f32x4*)(xb + idx));
        f32x4 r;
        r.x = v.x * sc.x + sh.x;
        r.y = v.y * sc.y + sh.y;
        r.z = v.z * sc.z + sh.z;
        r.w = v.w * sc.w + sh.w;
        __builtin_nontemporal_store(r, (f32x4*)(ob + idx));
    }
}

extern "C" void kernel_launch(void* const* d_in, const int* in_sizes, int n_in,
                              void* d_out, int out_size, void* d_ws, size_t ws_size,
                              hipStream_t stream) {
    const float* x     = (const float*)d_in[0];
    const float* gamma = (const float*)d_in[1];
    const float* beta  = (const float*)d_in[2];
    const int*   perm  = (const int*)d_in[3];
    float* out = (float*)d_out;

    // Workspace: asum | asq = 8 KB total (identical footprint to the
    // previously-verified kernel; sc/sh live in-place in asum/asq).
    float* asum = (float*)d_ws;
    float* asq  = asum + NP * NCH;

    k_zero<<<1, 256, 0, stream>>>(asum);
    k_partial<<<NB * SPLIT, 256, 0, stream>>>((const float4*)x, perm, asum, asq);
    k_finalize<<<1, 256, 0, stream>>>(asum, asq, gamma, beta);
    k_norm<<<NB * SPLIT, 256, 0, stream>>>((const float4*)x, (const float4*)asum,
                                           (const float4*)asq, perm, (float4*)out);
}